// Round 1
// baseline (643.057 us; speedup 1.0000x reference)
//
#include <hip/hip_runtime.h>

// ---------------------------------------------------------------------------
// MLA forward (B=1, S=2048, HID=2048, NH=32, DQK=192(128+64 rope), DV=128)
// Round 0: correct full pipeline, bf16 MFMA everywhere, m97-style GEMM.
// ---------------------------------------------------------------------------

typedef __bf16 bf16x8 __attribute__((ext_vector_type(8)));
typedef float  f32x4  __attribute__((ext_vector_type(4)));

#define GLOAD16(g, l)                                                          \
  __builtin_amdgcn_global_load_lds(                                            \
      (const __attribute__((address_space(1))) unsigned int*)(g),              \
      (__attribute__((address_space(3))) unsigned int*)(l), 16, 0, 0)

__device__ __forceinline__ unsigned short f2b(float f) {
  unsigned u = __builtin_bit_cast(unsigned, f);
  u += 0x7fffu + ((u >> 16) & 1u);   // round-to-nearest-even
  return (unsigned short)(u >> 16);
}

// ---------------- elementwise cast fp32 -> bf16 (vectorized) ----------------
__global__ __launch_bounds__(256) void castb(const float* __restrict__ s,
                                             unsigned short* __restrict__ d, int n4) {
  int i = blockIdx.x * 256 + threadIdx.x;
  if (i < n4) {
    float4 v = ((const float4*)s)[i];
    ushort4 o;
    o.x = f2b(v.x); o.y = f2b(v.y); o.z = f2b(v.z); o.w = f2b(v.w);
    ((ushort4*)d)[i] = o;
  }
}

// ------------- transpose-cast: src[R][C] f32 -> dst[Cpad][R] bf16 -----------
// Zero-fills rows C..Cpad (used to pad kv_a N=576 -> 640).
__global__ __launch_bounds__(256) void tcast(const float* __restrict__ src,
                                             unsigned short* __restrict__ dst,
                                             int R, int C, int Cpad) {
  __shared__ float t[32][33];
  int tx = threadIdx.x, ty = threadIdx.y;
  int r0 = blockIdx.x * 32, c0 = blockIdx.y * 32;
#pragma unroll
  for (int j = 0; j < 4; j++) {
    int c = c0 + tx;
    t[ty + j * 8][tx] = (c < C) ? src[(size_t)(r0 + ty + j * 8) * C + c] : 0.f;
  }
  __syncthreads();
#pragma unroll
  for (int j = 0; j < 4; j++)
    dst[(size_t)(c0 + ty + j * 8) * R + r0 + tx] = f2b(t[tx][ty + j * 8]);
}

// ---------------- RMSNorm row kernel: fp32 in -> bf16 out -------------------
__global__ __launch_bounds__(256) void rmsnorm(const float* __restrict__ x,
                                               const float* __restrict__ w,
                                               unsigned short* __restrict__ o,
                                               int C, int stride) {
  int row = blockIdx.x, tid = threadIdx.x;
  const float* xr = x + (size_t)row * stride;
  float ss = 0.f;
  for (int c = tid; c < C; c += 256) { float v = xr[c]; ss += v * v; }
#pragma unroll
  for (int off = 1; off < 64; off <<= 1) ss += __shfl_xor(ss, off, 64);
  __shared__ float red[4];
  if ((tid & 63) == 0) red[tid >> 6] = ss;
  __syncthreads();
  ss = red[0] + red[1] + red[2] + red[3];
  float r = rsqrtf(ss / C + 1e-6f);
  unsigned short* orow = o + (size_t)row * C;
  for (int c = tid; c < C; c += 256) orow[c] = f2b(xr[c] * r * w[c]);
}

// ------------- q RoPE + cast: q_raw[2048][6144] f32 -> Qb bf16 --------------
// per (s,h): d<128 passthrough, d in [128,192) = rope'd pairs (i, i+32)
__global__ __launch_bounds__(256) void qrope(const float* __restrict__ q,
                                             unsigned short* __restrict__ Qb) {
  int s = blockIdx.x, tid = threadIdx.x;
  const float* qr = q + (size_t)s * 6144;
  unsigned short* ob = Qb + (size_t)s * 6144;
  for (int idx = tid; idx < 6144; idx += 256) {
    int d = idx % 192;
    float v = qr[idx], outv;
    if (d < 128) outv = v;
    else {
      int i = d - 128, ii = i & 31;
      float inv = powf(10000.f, -(float)ii * (1.f / 32.f));
      float a = (float)s * inv;
      float cs = cosf(a), sn = sinf(a);
      if (i < 32) outv = v * cs - qr[idx + 32] * sn;
      else        outv = qr[idx - 32] * sn + v * cs;
    }
    ob[idx] = f2b(outv);
  }
}

// -------- k_rot rope + broadcast into Kb[t][h*192 + 128..192] ---------------
__global__ __launch_bounds__(256) void krot(const float* __restrict__ ckv,
                                            unsigned short* __restrict__ Kb) {
  int t = blockIdx.x, tid = threadIdx.x;
  __shared__ unsigned short rot[64];
  if (tid < 32) {
    float x1 = ckv[(size_t)t * 640 + 512 + tid];
    float x2 = ckv[(size_t)t * 640 + 544 + tid];
    float inv = powf(10000.f, -(float)tid * (1.f / 32.f));
    float a = (float)t * inv;
    float cs = cosf(a), sn = sinf(a);
    rot[tid]      = f2b(x1 * cs - x2 * sn);
    rot[tid + 32] = f2b(x1 * sn + x2 * cs);
  }
  __syncthreads();
  for (int idx = tid; idx < 2048; idx += 256) {
    int h = idx >> 6, d = idx & 63;
    Kb[(size_t)t * 6144 + h * 192 + 128 + d] = rot[d];
  }
}

// -------- k_pass split: kv_raw[t][h*256 + d] -> Kb[t][h*192 + d], d<128 -----
__global__ __launch_bounds__(256) void kvpass(const float* __restrict__ kv,
                                              unsigned short* __restrict__ Kb) {
  int t = blockIdx.x, tid = threadIdx.x;
  for (int idx = tid; idx < 4096; idx += 256) {
    int h = idx >> 7, d = idx & 127;
    Kb[(size_t)t * 6144 + h * 192 + d] = f2b(kv[(size_t)t * 8192 + h * 256 + d]);
  }
}

// -------- V transpose: kv_raw[t][h*256+128+d] -> Vt[h*128+d][t] bf16 --------
__global__ __launch_bounds__(256) void vtrans(const float* __restrict__ kv,
                                              unsigned short* __restrict__ Vt) {
  __shared__ float t[32][33];
  int tx = threadIdx.x, ty = threadIdx.y;
  int t0 = blockIdx.x * 32, d0 = blockIdx.y * 32, h = blockIdx.z;
#pragma unroll
  for (int j = 0; j < 4; j++)
    t[ty + j * 8][tx] = kv[(size_t)(t0 + ty + j * 8) * 8192 + h * 256 + 128 + d0 + tx];
  __syncthreads();
#pragma unroll
  for (int j = 0; j < 4; j++)
    Vt[(size_t)(h * 128 + d0 + ty + j * 8) * 2048 + t0 + tx] = f2b(t[tx][ty + j * 8]);
}

// ---------------------------------------------------------------------------
// GEMM: C[M][N] f32 = A[M][K] bf16 * Bt[N][K] bf16   (B given transposed)
// 128x128 tile, BK=32, 4 waves 2x2 (each 64x64 = 4x4 mfma 16x16x32 frags).
// global_load_lds width-16 staging; XOR chunk swizzle (source-side + read-side)
// keeps ds_read_b128 at the free 2-way conflict level.
// ---------------------------------------------------------------------------
__global__ __launch_bounds__(256) void gemm_bt(const unsigned short* __restrict__ A,
                                               const unsigned short* __restrict__ Bt,
                                               float* __restrict__ C,
                                               int M, int N, int K) {
  __shared__ unsigned short As[4096];  // [128 rows][32 k] bf16
  __shared__ unsigned short Bs[4096];
  const int tid = threadIdx.x;
  const int w = tid >> 6, lane = tid & 63;
  const int lr = lane & 15, lh = lane >> 4;
  const int m0 = blockIdx.y * 128, n0 = blockIdx.x * 128;
  const int wm = w >> 1, wn = w & 1;
  const int srow = lane >> 2;                          // staging row within 16-row group
  const int schunk = (lane & 3) ^ ((lane >> 3) & 3);   // pre-swizzled source chunk
  const int swzr = (lr >> 1) & 3;                      // read-side swizzle key

  f32x4 acc[4][4];
  const f32x4 z = {0.f, 0.f, 0.f, 0.f};
#pragma unroll
  for (int i = 0; i < 4; i++)
#pragma unroll
    for (int j = 0; j < 4; j++) acc[i][j] = z;

  for (int k0 = 0; k0 < K; k0 += 32) {
#pragma unroll
    for (int c = 0; c < 2; c++) {
      GLOAD16(A + (size_t)(m0 + c * 64 + w * 16 + srow) * K + k0 + schunk * 8,
              As + c * 2048 + w * 512);
      GLOAD16(Bt + (size_t)(n0 + c * 64 + w * 16 + srow) * K + k0 + schunk * 8,
              Bs + c * 2048 + w * 512);
    }
    __syncthreads();
    bf16x8 a[4], b[4];
#pragma unroll
    for (int m = 0; m < 4; m++) {
      int row = wm * 64 + m * 16 + lr;
      a[m] = *(const bf16x8*)(As + row * 32 + ((lh ^ swzr) * 8));
    }
#pragma unroll
    for (int n = 0; n < 4; n++) {
      int row = wn * 64 + n * 16 + lr;
      b[n] = *(const bf16x8*)(Bs + row * 32 + ((lh ^ swzr) * 8));
    }
#pragma unroll
    for (int m = 0; m < 4; m++)
#pragma unroll
      for (int n = 0; n < 4; n++)
        acc[m][n] = __builtin_amdgcn_mfma_f32_16x16x32_bf16(a[m], b[n], acc[m][n], 0, 0, 0);
    __syncthreads();
  }
#pragma unroll
  for (int m = 0; m < 4; m++)
#pragma unroll
    for (int n = 0; n < 4; n++)
#pragma unroll
      for (int r = 0; r < 4; r++) {
        int row = m0 + wm * 64 + m * 16 + lh * 4 + r;
        int col = n0 + wn * 64 + n * 16 + lr;
        C[(size_t)row * N + col] = acc[m][n][r];
      }
}

// ---------------------------------------------------------------------------
// Causal MLA attention. Grid (S/64, NH). Block 256 = 4 waves, wave w owns
// q rows [q0+16w, q0+16w+16). KV tiles of 32 staged in padded LDS.
// Qb[s][h*192+d] bf16 (rope'd), Kb[t][h*192+d] bf16, Vt[h*128+d][t] bf16.
// Out: O[s][h*128+d] bf16.
// ---------------------------------------------------------------------------
__global__ __launch_bounds__(256) void attn(const unsigned short* __restrict__ Qb,
                                            const unsigned short* __restrict__ Kb,
                                            const unsigned short* __restrict__ Vt,
                                            unsigned short* __restrict__ O) {
  __shared__ unsigned short Kl[32 * 200];   // [32 t][192+8 d]  (pad -> 2-way banks)
  __shared__ unsigned short Vl[128 * 40];   // [128 d][32+8 t]
  __shared__ unsigned short Pl[4][16 * 40]; // per-wave [16 q][32+8 t]
  const int tid = threadIdx.x;
  const int w = tid >> 6, lane = tid & 63;
  const int lr = lane & 15, lh = lane >> 4;
  const int h = blockIdx.y;
  const int q0 = blockIdx.x * 64;
  const int qw = q0 + w * 16;

  bf16x8 qf[6];
#pragma unroll
  for (int c = 0; c < 6; c++)
    qf[c] = *(const bf16x8*)(Qb + (size_t)(qw + lr) * 6144 + h * 192 + c * 32 + lh * 8);

  f32x4 acc[8];
  const f32x4 z = {0.f, 0.f, 0.f, 0.f};
#pragma unroll
  for (int n = 0; n < 8; n++) acc[n] = z;
  float m[4] = {-1e30f, -1e30f, -1e30f, -1e30f};
  float l[4] = {0.f, 0.f, 0.f, 0.f};
  const float scale = 0.07216878364870322f;  // 192^-0.5

  const int nt = (q0 + 64) >> 5;
  for (int it = 0; it < nt; ++it) {
    const int t0 = it << 5;
    __syncthreads();
#pragma unroll
    for (int j = 0; j < 3; j++) {          // K tile: 32 rows x 24 16B-chunks
      int g = tid + j * 256, row = g / 24, c = g - row * 24;
      *(int4*)(Kl + row * 200 + c * 8) =
          *(const int4*)(Kb + (size_t)(t0 + row) * 6144 + h * 192 + c * 8);
    }
#pragma unroll
    for (int j = 0; j < 2; j++) {          // V tile: 128 rows x 4 16B-chunks
      int g = tid + j * 256, d = g >> 2, c = g & 3;
      *(int4*)(Vl + d * 40 + c * 8) =
          *(const int4*)(Vt + (size_t)(h * 128 + d) * 2048 + t0 + c * 8);
    }
    __syncthreads();
    if (t0 <= qw + 15) {
      f32x4 s0 = z, s1 = z;
#pragma unroll
      for (int c = 0; c < 6; c++) {
        bf16x8 k0 = *(const bf16x8*)(Kl + lr * 200 + c * 32 + lh * 8);
        bf16x8 k1 = *(const bf16x8*)(Kl + (16 + lr) * 200 + c * 32 + lh * 8);
        s0 = __builtin_amdgcn_mfma_f32_16x16x32_bf16(qf[c], k0, s0, 0, 0, 0);
        s1 = __builtin_amdgcn_mfma_f32_16x16x32_bf16(qf[c], k1, s1, 0, 0, 0);
      }
      float rs[4];
#pragma unroll
      for (int r = 0; r < 4; r++) {
        const int qrow = qw + lh * 4 + r;
        float a0 = (t0 + lr > qrow) ? -1e30f : s0[r] * scale;
        float a1 = (t0 + 16 + lr > qrow) ? -1e30f : s1[r] * scale;
        float mx = fmaxf(a0, a1);
#pragma unroll
        for (int off = 1; off < 16; off <<= 1) mx = fmaxf(mx, __shfl_xor(mx, off, 16));
        float mn = fmaxf(m[r], mx);
        float ro = __expf(m[r] - mn);
        float p0 = __expf(a0 - mn), p1 = __expf(a1 - mn);
        float sum = p0 + p1;
#pragma unroll
        for (int off = 1; off < 16; off <<= 1) sum += __shfl_xor(sum, off, 16);
        l[r] = l[r] * ro + sum;
        m[r] = mn;
        rs[r] = ro;
        Pl[w][(lh * 4 + r) * 40 + lr]      = f2b(p0);
        Pl[w][(lh * 4 + r) * 40 + 16 + lr] = f2b(p1);
      }
#pragma unroll
      for (int n = 0; n < 8; n++)
#pragma unroll
        for (int r = 0; r < 4; r++) acc[n][r] *= rs[r];
      bf16x8 pa = *(const bf16x8*)(Pl[w] + lr * 40 + lh * 8);
#pragma unroll
      for (int n = 0; n < 8; n++) {
        bf16x8 vb = *(const bf16x8*)(Vl + (n * 16 + lr) * 40 + lh * 8);
        acc[n] = __builtin_amdgcn_mfma_f32_16x16x32_bf16(pa, vb, acc[n], 0, 0, 0);
      }
    }
  }
#pragma unroll
  for (int n = 0; n < 8; n++)
#pragma unroll
    for (int r = 0; r < 4; r++) {
      int q = qw + lh * 4 + r;
      O[(size_t)q * 4096 + h * 128 + n * 16 + lr] = f2b(acc[n][r] / l[r]);
    }
}

// ---------------------------------------------------------------------------
extern "C" void kernel_launch(void* const* d_in, const int* in_sizes, int n_in,
                              void* d_out, int out_size, void* d_ws, size_t ws_size,
                              hipStream_t stream) {
  const float* hs      = (const float*)d_in[0];
  const float* q_a_w   = (const float*)d_in[1];
  const float* q_a_ln  = (const float*)d_in[2];
  const float* q_b_w   = (const float*)d_in[3];
  const float* kv_a_w  = (const float*)d_in[4];
  const float* kv_a_ln = (const float*)d_in[5];
  const float* kv_b_w  = (const float*)d_in[6];
  const float* o_w     = (const float*)d_in[7];
  float* out = (float*)d_out;

  char* ws = (char*)d_ws;
  size_t off = 0;
  auto alloc = [&](size_t bytes) {
    void* p = ws + off;
    off += (bytes + 255) & ~(size_t)255;
    return p;
  };
  unsigned short* q_a_wT  = (unsigned short*)alloc(1536UL * 2048 * 2);
  unsigned short* q_b_wT  = (unsigned short*)alloc(6144UL * 1536 * 2);
  unsigned short* kv_a_wT = (unsigned short*)alloc(640UL * 2048 * 2);
  unsigned short* kv_b_wT = (unsigned short*)alloc(8192UL * 512 * 2);
  unsigned short* o_wT    = (unsigned short*)alloc(2048UL * 4096 * 2);
  unsigned short* hs_b    = (unsigned short*)alloc(2048UL * 2048 * 2);
  unsigned short* q_a_n   = (unsigned short*)alloc(2048UL * 1536 * 2);
  unsigned short* Qb      = (unsigned short*)alloc(2048UL * 6144 * 2);
  float*          ckv_raw = (float*)alloc(2048UL * 640 * 4);
  unsigned short* ckv_n   = (unsigned short*)alloc(2048UL * 512 * 2);
  unsigned short* Kb      = (unsigned short*)alloc(2048UL * 6144 * 2);
  unsigned short* Vt      = (unsigned short*)alloc(32UL * 128 * 2048 * 2);
  // Big transient region, time-shared: q_a_raw -> q_raw -> kv_raw -> attn_out
  float* big = (float*)alloc(2048UL * 8192 * 4);
  float* q_a_raw = big;
  float* q_raw   = big;
  float* kv_raw  = big;
  unsigned short* attn_out = (unsigned short*)big;
  (void)ws_size; (void)in_sizes; (void)n_in; (void)out_size;

  dim3 b256(256), b328(32, 8);
  // weight prep
  castb<<<4096, b256, 0, stream>>>(hs, hs_b, 1048576);
  tcast<<<dim3(64, 48), b328, 0, stream>>>(q_a_w, q_a_wT, 2048, 1536, 1536);
  tcast<<<dim3(48, 192), b328, 0, stream>>>(q_b_w, q_b_wT, 1536, 6144, 6144);
  tcast<<<dim3(64, 20), b328, 0, stream>>>(kv_a_w, kv_a_wT, 2048, 576, 640);
  tcast<<<dim3(16, 256), b328, 0, stream>>>(kv_b_w, kv_b_wT, 512, 8192, 8192);
  tcast<<<dim3(128, 64), b328, 0, stream>>>(o_w, o_wT, 4096, 2048, 2048);
  // q path
  gemm_bt<<<dim3(12, 16), b256, 0, stream>>>(hs_b, q_a_wT, q_a_raw, 2048, 1536, 2048);
  rmsnorm<<<2048, b256, 0, stream>>>(q_a_raw, q_a_ln, q_a_n, 1536, 1536);
  gemm_bt<<<dim3(48, 16), b256, 0, stream>>>(q_a_n, q_b_wT, q_raw, 2048, 6144, 1536);
  qrope<<<2048, b256, 0, stream>>>(q_raw, Qb);
  // kv path
  gemm_bt<<<dim3(5, 16), b256, 0, stream>>>(hs_b, kv_a_wT, ckv_raw, 2048, 640, 2048);
  rmsnorm<<<2048, b256, 0, stream>>>(ckv_raw, kv_a_ln, ckv_n, 512, 640);
  krot<<<2048, b256, 0, stream>>>(ckv_raw, Kb);
  gemm_bt<<<dim3(64, 16), b256, 0, stream>>>(ckv_n, kv_b_wT, kv_raw, 2048, 8192, 512);
  kvpass<<<2048, b256, 0, stream>>>(kv_raw, Kb);
  vtrans<<<dim3(64, 4, 32), b328, 0, stream>>>(kv_raw, Vt);
  // attention + output projection
  attn<<<dim3(32, 32), b256, 0, stream>>>(Qb, Kb, Vt, attn_out);
  gemm_bt<<<dim3(16, 16), b256, 0, stream>>>(attn_out, o_wT, out, 2048, 2048, 4096);
}